// Round 10
// baseline (6336.135 us; speedup 1.0000x reference)
//
#include <hip/hip_runtime.h>
#include <cmath>

// RNN: T=2048, B=64, I=H=512, fp32 in/out.
// Phase 1: xw_gemm — f16-MFMA GEMM: xw = x @ W_ih^T + (b_ih+b_hh) -> d_out.
// Phase 2: rnn_scan — 64 WGs (1/batch) x 256 thr (4 waves, 1 wave/SIMD,
//   512-reg budget). Wave w owns rows [128w,128w+128): 8 row-blocks x 16
//   k-chunks. W_hh f16: 12 chunks in registers (384 regs, unified VGPR/AGPR
//   file, MFMA reads AGPR directly), 4 chunks in LDS (128 KB). No L2 stream.
//   LDS/step/CU: 64 A-broadcasts + 128 W-reads = 192 b128 (~2300 cy) under
//   the 2482-cy MFMA floor. h triple-buffered fp16, lgkm-only barrier.

#define SEQ_T 2048
#define BATCH 64
#define KDIM 512
#define HDIM 512

typedef __fp16 h2v __attribute__((ext_vector_type(2)));
typedef __fp16 f16x8 __attribute__((ext_vector_type(8)));
typedef float f32x4 __attribute__((ext_vector_type(4)));

static __device__ __forceinline__ f16x8 pk8(float4 a, float4 b) {
  h2v p0 = __builtin_amdgcn_cvt_pkrtz(a.x, a.y);
  h2v p1 = __builtin_amdgcn_cvt_pkrtz(a.z, a.w);
  h2v p2 = __builtin_amdgcn_cvt_pkrtz(b.x, b.y);
  h2v p3 = __builtin_amdgcn_cvt_pkrtz(b.z, b.w);
  f16x8 r;
  r[0] = p0[0]; r[1] = p0[1]; r[2] = p1[0]; r[3] = p1[1];
  r[4] = p2[0]; r[5] = p2[1]; r[6] = p3[0]; r[7] = p3[1];
  return r;
}

// ================= Phase 1: f16 MFMA GEMM ===================================
#define G_LDA 72  // f16 units per row (144 B)

#define MFM(mt, nt) \
  d##mt##nt = __builtin_amdgcn_mfma_f32_16x16x32_f16(fa##mt, fb##nt, d##mt##nt, 0, 0, 0);

#define EPI(mt, nt, bb)                                                     \
  {                                                                         \
    int row = m0 + wm + mt * 16 + (l >> 4) * 4;                             \
    int col = n0 + wn + nt * 16 + (l & 15);                                 \
    out[(size_t)(row + 0) * HDIM + col] = d##mt##nt[0] + bb;                \
    out[(size_t)(row + 1) * HDIM + col] = d##mt##nt[1] + bb;                \
    out[(size_t)(row + 2) * HDIM + col] = d##mt##nt[2] + bb;                \
    out[(size_t)(row + 3) * HDIM + col] = d##mt##nt[3] + bb;                \
  }

__global__ __launch_bounds__(256) void xw_gemm(const float* __restrict__ x,
                                               const float* __restrict__ Wih,
                                               const float* __restrict__ bih,
                                               const float* __restrict__ bhh,
                                               float* __restrict__ out) {
  __shared__ __fp16 At[128 * G_LDA];
  __shared__ __fp16 Bt[64 * G_LDA];
  const int tid = threadIdx.x;
  const int l = tid & 63;
  const int w = tid >> 6;
  const int m0 = (blockIdx.x >> 3) * 128;
  const int n0 = (blockIdx.x & 7) * 64;
  const int wm = (w >> 1) * 64;
  const int wn = (w & 1) * 32;

  const float bias0 = bih[n0 + wn + (l & 15)] + bhh[n0 + wn + (l & 15)];
  const float bias1 = bih[n0 + wn + 16 + (l & 15)] + bhh[n0 + wn + 16 + (l & 15)];

  f32x4 d00 = {0,0,0,0}, d01 = {0,0,0,0}, d10 = {0,0,0,0}, d11 = {0,0,0,0};
  f32x4 d20 = {0,0,0,0}, d21 = {0,0,0,0}, d30 = {0,0,0,0}, d31 = {0,0,0,0};

  for (int k0 = 0; k0 < KDIM; k0 += 64) {
    __syncthreads();
#pragma unroll
    for (int p = 0; p < 4; ++p) {
      int idx = tid + p * 256;
      int r = idx >> 3, sg = idx & 7;
      const float* ps = x + (size_t)(m0 + r) * KDIM + k0 + sg * 8;
      *(f16x8*)(At + r * G_LDA + sg * 8) =
          pk8(*(const float4*)ps, *(const float4*)(ps + 4));
    }
#pragma unroll
    for (int p = 0; p < 2; ++p) {
      int idx = tid + p * 256;
      int r = idx >> 3, sg = idx & 7;
      const float* ps = Wih + (size_t)(n0 + r) * KDIM + k0 + sg * 8;
      *(f16x8*)(Bt + r * G_LDA + sg * 8) =
          pk8(*(const float4*)ps, *(const float4*)(ps + 4));
    }
    __syncthreads();
#pragma unroll
    for (int kk = 0; kk < 2; ++kk) {
      const int kc = kk * 32 + (l >> 4) * 8;
      f16x8 fa0 = *(const f16x8*)(At + (wm + 0 * 16 + (l & 15)) * G_LDA + kc);
      f16x8 fa1 = *(const f16x8*)(At + (wm + 1 * 16 + (l & 15)) * G_LDA + kc);
      f16x8 fa2 = *(const f16x8*)(At + (wm + 2 * 16 + (l & 15)) * G_LDA + kc);
      f16x8 fa3 = *(const f16x8*)(At + (wm + 3 * 16 + (l & 15)) * G_LDA + kc);
      f16x8 fb0 = *(const f16x8*)(Bt + (wn + 0 * 16 + (l & 15)) * G_LDA + kc);
      f16x8 fb1 = *(const f16x8*)(Bt + (wn + 1 * 16 + (l & 15)) * G_LDA + kc);
      MFM(0, 0) MFM(1, 0) MFM(2, 0) MFM(3, 0)
      MFM(0, 1) MFM(1, 1) MFM(2, 1) MFM(3, 1)
    }
  }

  EPI(0, 0, bias0) EPI(1, 0, bias0) EPI(2, 0, bias0) EPI(3, 0, bias0)
  EPI(0, 1, bias1) EPI(1, 1, bias1) EPI(2, 1, bias1) EPI(3, 1, bias1)
}

// ================= Phase 2: MFMA recurrence (4 waves, big-reg) ==============
// Wave w rows [128w,128w+128), row-blocks c=0..7 (rows 128w+16c+(l&15)).
// B-frag(c,n) lane l = W[128w+16c+(l&15)][32n+8(l>>4)+e], e=0..7.
// A-frag(n) = h[32n+8(l>>4)+e], replicated -> D rows identical.
// n=0..11 in registers; n=12..15 in LDS at slot ((n-12)*8+c)*4096 + tid*16.

#define REPC(M, n) M(0,n) M(1,n) M(2,n) M(3,n) M(4,n) M(5,n) M(6,n) M(7,n)

#define DECLB(c, n) f16x8 bf##c##_##n;
#define LOADB(c, n)                                                  \
  {                                                                  \
    const float* p = wr##c + 32 * n;                                 \
    bf##c##_##n = pk8(*(const float4*)p, *(const float4*)(p + 4));   \
  }
#define STOREB(c, n)                                                 \
  {                                                                  \
    const float* p = wr##c + 32 * n;                                 \
    *(f16x8*)(ldsm + (((n) - 12) * 8 + c) * 4096 + (tid << 4)) =     \
        pk8(*(const float4*)p, *(const float4*)(p + 4));             \
  }

#define MF(c, n) \
  d##c = __builtin_amdgcn_mfma_f32_16x16x32_f16(acur, bf##c##_##n, d##c, 0, 0, 0);
#define MFL(c, n)                                                               \
  {                                                                             \
    f16x8 bl = *(const f16x8*)(ldsm + (((n) - 12) * 8 + c) * 4096 + (tid << 4)); \
    d##c = __builtin_amdgcn_mfma_f32_16x16x32_f16(acur, bl, d##c, 0, 0, 0);     \
  }

#define CH(n, nn)                                                \
  {                                                              \
    f16x8 anx = *(const f16x8*)(hcv + 64 * (nn) + goff);         \
    MF(0, n) MF(1, n) MF(2, n) MF(3, n)                          \
    MF(4, n) MF(5, n) MF(6, n) MF(7, n)                          \
    acur = anx;                                                  \
  }
#define CHL(n, nn)                                               \
  {                                                              \
    f16x8 anx = *(const f16x8*)(hcv + 64 * (nn) + goff);         \
    MFL(0, n) MFL(1, n) MFL(2, n) MFL(3, n)                      \
    MFL(4, n) MFL(5, n) MFL(6, n) MFL(7, n)                      \
    acur = anx;                                                  \
  }

#define WLDS_BYTES (32 * 4096)             // 131072 (chunks 12..15)
#define HBUF0 WLDS_BYTES
#define LDS_TOTAL (WLDS_BYTES + 3 * 1024)  // 134144

#define BAR()                                              \
  asm volatile("s_waitcnt lgkmcnt(0)" ::: "memory");       \
  __builtin_amdgcn_sched_barrier(0);                       \
  __builtin_amdgcn_s_barrier();                            \
  __builtin_amdgcn_sched_barrier(0);

__global__ __attribute__((amdgpu_flat_work_group_size(256, 256),
                          amdgpu_waves_per_eu(1, 1)))
void rnn_scan(const float* __restrict__ Whh, float* __restrict__ io) {
  extern __shared__ __align__(16) char ldsm[];
  const int tid = threadIdx.x;
  const int b = blockIdx.x;
  const int l = tid & 63;
  const int w = tid >> 6;
  const int m16 = l & 15;
  const int gh = l >> 4;
  const int goff = gh << 4;
  const int rb = w << 7;       // wave's first row (128 per wave)
  const int jo0 = rb + l;      // lane finalizes rows jo0 and jo1
  const int jo1 = rb + 64 + l;

  const float* wr0 = Whh + (size_t)(rb + 0   + m16) * KDIM + 8 * gh;
  const float* wr1 = Whh + (size_t)(rb + 16  + m16) * KDIM + 8 * gh;
  const float* wr2 = Whh + (size_t)(rb + 32  + m16) * KDIM + 8 * gh;
  const float* wr3 = Whh + (size_t)(rb + 48  + m16) * KDIM + 8 * gh;
  const float* wr4 = Whh + (size_t)(rb + 64  + m16) * KDIM + 8 * gh;
  const float* wr5 = Whh + (size_t)(rb + 80  + m16) * KDIM + 8 * gh;
  const float* wr6 = Whh + (size_t)(rb + 96  + m16) * KDIM + 8 * gh;
  const float* wr7 = Whh + (size_t)(rb + 112 + m16) * KDIM + 8 * gh;

  // chunks 0..11 resident in the unified VGPR/AGPR file (384 regs)
  REPC(DECLB, 0)  REPC(DECLB, 1)  REPC(DECLB, 2)  REPC(DECLB, 3)
  REPC(DECLB, 4)  REPC(DECLB, 5)  REPC(DECLB, 6)  REPC(DECLB, 7)
  REPC(DECLB, 8)  REPC(DECLB, 9)  REPC(DECLB, 10) REPC(DECLB, 11)
  REPC(LOADB, 0)  REPC(LOADB, 1)  REPC(LOADB, 2)  REPC(LOADB, 3)
  REPC(LOADB, 4)  REPC(LOADB, 5)  REPC(LOADB, 6)  REPC(LOADB, 7)
  REPC(LOADB, 8)  REPC(LOADB, 9)  REPC(LOADB, 10) REPC(LOADB, 11)

  // chunks 12..15 in LDS (128 KB)
  REPC(STOREB, 12) REPC(STOREB, 13) REPC(STOREB, 14) REPC(STOREB, 15)

  // zero h buffer 0 (fp16[512])
  ((unsigned short*)(ldsm + HBUF0))[tid] = 0;
  ((unsigned short*)(ldsm + HBUF0))[tid + 256] = 0;
  __syncthreads();

  char* hcur = ldsm + HBUF0;
  char* hnxt = ldsm + HBUF0 + 1024;
  char* hthr = ldsm + HBUF0 + 2048;

  float* iorow = io + (size_t)b * HDIM;

  for (int t = 0; t < SEQ_T; ++t) {
    float uin0 = iorow[jo0];
    float uin1 = iorow[jo1];

    const char* hcv = hcur;
    f16x8 acur = *(const f16x8*)(hcv + goff);

    f32x4 d0 = {0.f,0.f,0.f,0.f}, d1 = {0.f,0.f,0.f,0.f};
    f32x4 d2 = {0.f,0.f,0.f,0.f}, d3 = {0.f,0.f,0.f,0.f};
    f32x4 d4 = {0.f,0.f,0.f,0.f}, d5 = {0.f,0.f,0.f,0.f};
    f32x4 d6 = {0.f,0.f,0.f,0.f}, d7 = {0.f,0.f,0.f,0.f};

    CH(0, 1)   CH(1, 2)   CH(2, 3)   CH(3, 4)
    CH(4, 5)   CH(5, 6)   CH(6, 7)   CH(7, 8)
    CH(8, 9)   CH(9, 10)  CH(10, 11) CH(11, 12)
    CHL(12, 13) CHL(13, 14) CHL(14, 15) CHL(15, 15)

    // D rows identical; d_c[0] = z for row 128w+16c+m16, col m16.
    // lane l: rows jo0 = rb+l (c = l>>4) and jo1 = rb+64+l (c = 4+(l>>4)).
    float za0 = (l & 16) ? d1[0] : d0[0];
    float zb0 = (l & 16) ? d3[0] : d2[0];
    float z0s = (l & 32) ? zb0 : za0;
    float za1 = (l & 16) ? d5[0] : d4[0];
    float zb1 = (l & 16) ? d7[0] : d6[0];
    float z1s = (l & 32) ? zb1 : za1;

    float z0 = uin0 + z0s;
    float z1 = uin1 + z1s;
    float e0 = __expf(2.0f * z0);
    float e1 = __expf(2.0f * z1);
    float h0 = 1.0f - 2.0f * __builtin_amdgcn_rcpf(e0 + 1.0f);
    float h1 = 1.0f - 2.0f * __builtin_amdgcn_rcpf(e1 + 1.0f);
    iorow[jo0] = h0;
    iorow[jo1] = h1;
    *(__fp16*)(hnxt + 2 * jo0) = (__fp16)h0;
    *(__fp16*)(hnxt + 2 * jo1) = (__fp16)h1;

    char* tmp = hcur;
    hcur = hnxt; hnxt = hthr; hthr = tmp;
    iorow += (size_t)BATCH * HDIM;
    BAR();
  }
}

extern "C" void kernel_launch(void* const* d_in, const int* in_sizes, int n_in,
                              void* d_out, int out_size, void* d_ws, size_t ws_size,
                              hipStream_t stream) {
  const float* x = (const float*)d_in[0];
  const float* Wih = (const float*)d_in[1];
  const float* Whh = (const float*)d_in[2];
  const float* bih = (const float*)d_in[3];
  const float* bhh = (const float*)d_in[4];
  float* out = (float*)d_out;

  (void)hipFuncSetAttribute((const void*)rnn_scan,
                            hipFuncAttributeMaxDynamicSharedMemorySize,
                            LDS_TOTAL);

  const int M = SEQ_T * BATCH;
  dim3 g1((M / 128) * (HDIM / 64));  // 8192
  xw_gemm<<<g1, 256, 0, stream>>>(x, Wih, bih, bhh, out);

  rnn_scan<<<BATCH, 256, LDS_TOTAL, stream>>>(Whh, out);
}